// Round 2
// baseline (468.174 us; speedup 1.0000x reference)
//
#include <hip/hip_runtime.h>
#include <hip/hip_bf16.h>

typedef __hip_bfloat16 bf16;
typedef __attribute__((ext_vector_type(8))) short          bf16x8;
typedef __attribute__((ext_vector_type(4))) float          f32x4;
typedef __attribute__((ext_vector_type(8))) unsigned short u16x8;

#define C_DIM 512
#define NSP   4096

__device__ __forceinline__ float bf2f(unsigned short u) {
  union { unsigned int i; float f; } x; x.i = ((unsigned int)u) << 16; return x.f;
}

// ---------------- f32 -> bf16 convert (weights: 512x512) ----------------
__global__ __launch_bounds__(256) void cvt_bf16(const float* __restrict__ s,
                                                bf16* __restrict__ d) {
  const int i = (blockIdx.x * 256 + threadIdx.x) * 4;
  const float4 v = *reinterpret_cast<const float4*>(s + i);
  d[i + 0] = __float2bfloat16(v.x);
  d[i + 1] = __float2bfloat16(v.y);
  d[i + 2] = __float2bfloat16(v.z);
  d[i + 3] = __float2bfloat16(v.w);
}

// ---------------- x (B,C,N) f32 -> XT (B*N, C) bf16 ----------------
__global__ __launch_bounds__(256) void transpose_x(const float* __restrict__ x,
                                                   bf16* __restrict__ xt) {
  __shared__ float tile[32][33];
  const int n0 = blockIdx.x * 32, c0 = blockIdx.y * 32, b = blockIdx.z;
  const int tx = threadIdx.x & 31, ty = threadIdx.x >> 5;   // ty: 0..7
  const float* src = x + ((size_t)b * C_DIM + c0) * NSP + n0;
  #pragma unroll
  for (int i = 0; i < 32; i += 8)
    tile[ty + i][tx] = src[(size_t)(ty + i) * NSP + tx];    // [c_local][n_local]
  __syncthreads();
  bf16* dst = xt + ((size_t)b * NSP + n0) * C_DIM + c0;
  #pragma unroll
  for (int i = 0; i < 32; i += 8)
    dst[(size_t)(ty + i) * C_DIM + tx] = __float2bfloat16(tile[tx][ty + i]);
}

// ---------------- NT MFMA GEMM: C[m,n] = sum_k A[m,k]*B[n,k] ----------------
// 128x128 tile, BK=32, 256 threads (4 waves as 2x2 of 64x64), 16x16x32 bf16 MFMA.
// EPI: 0 bf16 +bias                (row-major, ldc)
//      1 bf16 *scale               (row-major, ldc; + bz*sC)
//      2 bf16 +bias, TRANSPOSED    (out[(b*C + n)*NSP + m], b = m>>12)
//      3 bf16 plain                (row-major, ldc; + bz*sC)
//      4 f32  +bias+resid, TRANSP. (same addressing as 2)
template<int EPI>
__global__ __launch_bounds__(256)
void gemm_nt(const bf16* __restrict__ A, const bf16* __restrict__ B,
             const float* __restrict__ bias, const float* __restrict__ resid,
             void* __restrict__ Cout,
             int K, int lda, int ldb, int ldc,
             long sA, long sB, long sC, float scale)
{
  __shared__ char smem[2][16384];   // per buf: A tile 8KB | B tile 8KB
  const int t  = threadIdx.x;
  const int m0 = blockIdx.y * 128;
  const int n0 = blockIdx.x * 128;
  const int bz = blockIdx.z;
  A += (size_t)bz * sA + (size_t)m0 * lda;
  B += (size_t)bz * sB + (size_t)n0 * ldb;

  const int lane = t & 63;
  const int wv = t >> 6;
  const int wr = wv >> 1, wc = wv & 1;

  f32x4 acc[4][4];
  #pragma unroll
  for (int i = 0; i < 4; ++i)
    #pragma unroll
    for (int j = 0; j < 4; ++j) acc[i][j] = (f32x4)0.0f;

  // Stage a 128x32 bf16 tile (linear LDS dest; XOR-swizzle applied to the
  // GLOBAL source granule so that swizzled reads see logical data: rule #21).
  auto STAGE = [&](int buf, int kt) {
    const bf16* a = A + kt * 32;
    const bf16* b = B + kt * 32;
    #pragma unroll
    for (int i = 0; i < 2; ++i) {
      const int chunk = i * 256 + t;          // 0..511 -> rows 0..127, 4 x 16B
      const int row = chunk >> 2, gp = chunk & 3;
      const int gg = gp ^ (row & 3);
      __builtin_amdgcn_global_load_lds(
          (const __attribute__((address_space(1))) unsigned int*)(a + (size_t)row * lda + gg * 8),
          (__attribute__((address_space(3))) unsigned int*)(&smem[buf][chunk * 16]),
          16, 0, 0);
    }
    #pragma unroll
    for (int i = 0; i < 2; ++i) {
      const int chunk = i * 256 + t;
      const int row = chunk >> 2, gp = chunk & 3;
      const int gg = gp ^ (row & 3);
      __builtin_amdgcn_global_load_lds(
          (const __attribute__((address_space(1))) unsigned int*)(b + (size_t)row * ldb + gg * 8),
          (__attribute__((address_space(3))) unsigned int*)(&smem[buf][8192 + chunk * 16]),
          16, 0, 0);
    }
  };

  const int nk = K >> 5;
  STAGE(0, 0);
  int cur = 0;
  const int gx   = ((lane >> 4) ^ (lane & 3)) * 16;  // swizzled 16B-granule offset
  const int arow = wr * 64 + (lane & 15);
  const int brow = wc * 64 + (lane & 15);

  for (int kt = 0; kt < nk; ++kt) {
    __syncthreads();                       // drains stage into cur (vmcnt0+barrier)
    if (kt + 1 < nk) STAGE(cur ^ 1, kt + 1);
    bf16x8 af[4], bg[4];
    #pragma unroll
    for (int i = 0; i < 4; ++i)
      af[i] = *reinterpret_cast<const bf16x8*>(&smem[cur][(arow + i * 16) * 64 + gx]);
    #pragma unroll
    for (int j = 0; j < 4; ++j)
      bg[j] = *reinterpret_cast<const bf16x8*>(&smem[cur][8192 + (brow + j * 16) * 64 + gx]);
    #pragma unroll
    for (int i = 0; i < 4; ++i)
      #pragma unroll
      for (int j = 0; j < 4; ++j)
        acc[i][j] = __builtin_amdgcn_mfma_f32_16x16x32_bf16(af[i], bg[j], acc[i][j], 0, 0, 0);
    cur ^= 1;
  }

  // Epilogue. Verified C/D map: col = lane&15, row = (lane>>4)*4 + reg.
  const int mq = (lane >> 4) * 4;
  const int nc = lane & 15;
  #pragma unroll
  for (int i = 0; i < 4; ++i) {
    #pragma unroll
    for (int j = 0; j < 4; ++j) {
      const int mm = m0 + wr * 64 + i * 16 + mq;   // rows mm..mm+3
      const int nn = n0 + wc * 64 + j * 16 + nc;
      const f32x4 v = acc[i][j];
      if (EPI == 0) {
        const float bi = bias[nn];
        bf16* o = (bf16*)Cout;
        #pragma unroll
        for (int q = 0; q < 4; ++q)
          o[(size_t)(mm + q) * ldc + nn] = __float2bfloat16(v[q] + bi);
      } else if (EPI == 1) {
        bf16* o = (bf16*)Cout + (size_t)bz * sC;
        #pragma unroll
        for (int q = 0; q < 4; ++q)
          o[(size_t)(mm + q) * ldc + nn] = __float2bfloat16(v[q] * scale);
      } else if (EPI == 3) {
        bf16* o = (bf16*)Cout + (size_t)bz * sC;
        #pragma unroll
        for (int q = 0; q < 4; ++q)
          o[(size_t)(mm + q) * ldc + nn] = __float2bfloat16(v[q]);
      } else if (EPI == 2) {
        const float bi = bias[nn];
        const int b = mm >> 12, ms = mm & (NSP - 1);
        bf16* o = (bf16*)Cout + ((size_t)b * C_DIM + nn) * NSP + ms;
        #pragma unroll
        for (int q = 0; q < 4; ++q) o[q] = __float2bfloat16(v[q] + bi);
      } else {  // EPI == 4
        const float bi = bias[nn];
        const int b = mm >> 12, ms = mm & (NSP - 1);
        const size_t off = ((size_t)b * C_DIM + nn) * NSP + ms;
        float* o = (float*)Cout + off;
        const float* r = resid + off;
        #pragma unroll
        for (int q = 0; q < 4; ++q) o[q] = v[q] + bi + r[q];
      }
    }
  }
}

// ---------------- row softmax on bf16 4096-wide rows, in place ----------------
__global__ __launch_bounds__(256) void softmax_bf16(bf16* __restrict__ S) {
  const size_t row = blockIdx.x;
  unsigned short* rp = reinterpret_cast<unsigned short*>(S) + row * NSP;
  const int t = threadIdx.x;
  const u16x8 v0 = reinterpret_cast<const u16x8*>(rp)[t];
  const u16x8 v1 = reinterpret_cast<const u16x8*>(rp)[t + 256];
  float f[16];
  #pragma unroll
  for (int j = 0; j < 8; ++j) { f[j] = bf2f(v0[j]); f[8 + j] = bf2f(v1[j]); }
  float mx = f[0];
  #pragma unroll
  for (int j = 1; j < 16; ++j) mx = fmaxf(mx, f[j]);
  #pragma unroll
  for (int o = 32; o; o >>= 1) mx = fmaxf(mx, __shfl_xor(mx, o));
  __shared__ float red[8];
  const int wv = t >> 6;
  if ((t & 63) == 0) red[wv] = mx;
  __syncthreads();
  mx = fmaxf(fmaxf(red[0], red[1]), fmaxf(red[2], red[3]));
  float sum = 0.0f;
  #pragma unroll
  for (int j = 0; j < 16; ++j) { f[j] = __expf(f[j] - mx); sum += f[j]; }
  #pragma unroll
  for (int o = 32; o; o >>= 1) sum += __shfl_xor(sum, o);
  if ((t & 63) == 0) red[4 + wv] = sum;
  __syncthreads();
  const float rs = 1.0f / (red[4] + red[5] + red[6] + red[7]);
  u16x8 w0, w1;
  #pragma unroll
  for (int j = 0; j < 8; ++j) {
    bf16 a = __float2bfloat16(f[j] * rs);
    bf16 b = __float2bfloat16(f[8 + j] * rs);
    w0[j] = *reinterpret_cast<unsigned short*>(&a);
    w1[j] = *reinterpret_cast<unsigned short*>(&b);
  }
  reinterpret_cast<u16x8*>(rp)[t] = w0;
  reinterpret_cast<u16x8*>(rp)[t + 256] = w1;
}

extern "C" void kernel_launch(void* const* d_in, const int* in_sizes, int n_in,
                              void* d_out, int out_size, void* d_ws, size_t ws_size,
                              hipStream_t stream)
{
  const float* x     = (const float*)d_in[0];
  const float* w_th  = (const float*)d_in[1];
  const float* b_th  = (const float*)d_in[2];
  const float* w_ph  = (const float*)d_in[3];
  const float* b_ph  = (const float*)d_in[4];
  const float* w_g   = (const float*)d_in[5];
  const float* b_g   = (const float*)d_in[6];
  const float* w_out = (const float*)d_in[7];
  const float* b_out = (const float*)d_in[8];

  const size_t NC = (size_t)16384 * C_DIM;    // activation elems (B*N, C)
  char* p = (char*)d_ws;
  auto take = [&](size_t bytes) {
    char* r = p; p += (bytes + 255) & ~(size_t)255; return r;
  };
  bf16* XT   = (bf16*)take(NC * 2);
  bf16* YT   = (bf16*)take(NC * 2);
  bf16* THT  = (bf16*)take(NC * 2);
  bf16* PHT  = (bf16*)take(NC * 2);
  bf16* G2   = (bf16*)take(NC * 2);           // (B, C, N) layout
  bf16* ZT   = (bf16*)take(NC * 2);
  bf16* WTH  = (bf16*)take((size_t)C_DIM * C_DIM * 2);
  bf16* WPH  = (bf16*)take((size_t)C_DIM * C_DIM * 2);
  bf16* WG   = (bf16*)take((size_t)C_DIM * C_DIM * 2);
  bf16* WOUT = (bf16*)take((size_t)C_DIM * C_DIM * 2);
  const size_t used = (size_t)(p - (char*)d_ws);
  const size_t S1 = (size_t)NSP * NSP * 2;    // one batch of scores, bf16
  const bool big = ws_size >= used + 4 * S1 + 1024;
  bf16* S = (bf16*)take(big ? 4 * S1 : S1);

  const dim3 blk(256);
  const float scale = 0.044194173824159216f;  // 512^-0.5
  const long sact = (long)NSP * C_DIM;        // per-batch activation stride
  const long sS   = (long)NSP * NSP;

  // weight converts (512x512 each; 262144/4/256 = 256 blocks)
  cvt_bf16<<<dim3(256), blk, 0, stream>>>(w_th,  WTH);
  cvt_bf16<<<dim3(256), blk, 0, stream>>>(w_ph,  WPH);
  cvt_bf16<<<dim3(256), blk, 0, stream>>>(w_g,   WG);
  cvt_bf16<<<dim3(256), blk, 0, stream>>>(w_out, WOUT);

  transpose_x<<<dim3(NSP / 32, C_DIM / 32, 4), blk, 0, stream>>>(x, XT);

  const dim3 gConv(C_DIM / 128, 16384 / 128, 1);   // (4, 128)
  // Y = g-conv(x)
  gemm_nt<0><<<gConv, blk, 0, stream>>>(XT, WG,  b_g,  nullptr, YT,  512, 512, 512, 512, 0, 0, 0, 1.0f);
  // theta / phi / g from Y
  gemm_nt<0><<<gConv, blk, 0, stream>>>(YT, WTH, b_th, nullptr, THT, 512, 512, 512, 512, 0, 0, 0, 1.0f);
  gemm_nt<0><<<gConv, blk, 0, stream>>>(YT, WPH, b_ph, nullptr, PHT, 512, 512, 512, 512, 0, 0, 0, 1.0f);
  gemm_nt<2><<<gConv, blk, 0, stream>>>(YT, WG,  b_g,  nullptr, G2,  512, 512, 512, 0,   0, 0, 0, 1.0f);

  if (big) {
    gemm_nt<1><<<dim3(32, 32, 4), blk, 0, stream>>>(THT, PHT, nullptr, nullptr, S,
        512, 512, 512, NSP, sact, sact, sS, scale);
    softmax_bf16<<<dim3(4 * NSP), blk, 0, stream>>>(S);
    gemm_nt<3><<<dim3(4, 32, 4), blk, 0, stream>>>(S, G2, nullptr, nullptr, ZT,
        4096, 4096, 4096, 512, sS, sact, sact, 1.0f);
  } else {
    for (int b = 0; b < 4; ++b) {
      gemm_nt<1><<<dim3(32, 32, 1), blk, 0, stream>>>(THT + sact * b, PHT + sact * b,
          nullptr, nullptr, S, 512, 512, 512, NSP, 0, 0, 0, scale);
      softmax_bf16<<<dim3(NSP), blk, 0, stream>>>(S);
      gemm_nt<3><<<dim3(4, 32, 1), blk, 0, stream>>>(S, G2 + sact * b, nullptr, nullptr,
          ZT + sact * b, 4096, 4096, 4096, 512, 0, 0, 0, 1.0f);
    }
  }

  // out = x + out-conv(z)   (f32, transposed store + residual)
  gemm_nt<4><<<gConv, blk, 0, stream>>>(ZT, WOUT, b_out, x, d_out,
      512, 512, 512, 0, 0, 0, 0, 1.0f);
}